// Round 1
// baseline (881.516 us; speedup 1.0000x reference)
//
#include <hip/hip_runtime.h>

// Problem shape (fixed): x (16,32,512,512) fp32, params (16,5) fp32,
// small_h = small_w = 256. Output (16,32,256,256) fp32.
constexpr int N_  = 16;
constexpr int C_  = 32;
constexpr int H_  = 512;
constexpr int W_  = 512;
constexpr int SH_ = 256;
constexpr int SW_ = 256;

// LDS staging buffer for one channel's source bbox of a 16x16 output tile.
// Bound: d(ix)/dw = 2a, d(ix)/dh = 2b with |a|+|b| <= sx*|cos|+|sin| <= sqrt(2)
// (|sx|,|sy| <= 1 for this problem). Span over 15 px: 2*sqrt(2)*15 = 42.5;
// +1 (x1 tap) +1 (floor) +2 (fp safety margins) -> <= 47. Allocate 50.
// Runtime block-uniform fallback to direct gather if exceeded.
constexpr int LDSH = 50;
constexpr int LDSW = 50;
constexpr int LDSS = 51;   // row stride in floats; odd -> decorrelated banks

// Source coordinate along one axis (W_ == H_ == 512 so one formula serves
// both): out index k in [0,256), grid = (2*(2k)+1)/512 - 1, then affine,
// then unnormalize. MUST match the per-pixel math bit-exactly (it does:
// corners call the same function).
__device__ __forceinline__ float src_coord(float ca, float cb, float cbias,
                                           int wk, int hk) {
    const float gx = (2.0f * (float)(2 * wk) + 1.0f) * (1.0f / (float)W_) - 1.0f;
    const float gy = (2.0f * (float)(2 * hk) + 1.0f) * (1.0f / (float)H_) - 1.0f;
    const float s  = ca * gx + cb * gy + cbias;
    return ((s + 1.0f) * (float)W_ - 1.0f) * 0.5f;
}

__global__ __launch_bounds__(256) void affine_sample_kernel(
    const float* __restrict__ x,      // (N, C, H, W)
    const float* __restrict__ params, // (N, 5): theta, sx, sy, tx, ty
    float* __restrict__ out)          // (N, C, SH, SW)
{
    __shared__ float tile[LDSH * LDSS];

    const int lx = threadIdx.x;
    const int ly = threadIdx.y;
    const int w  = blockIdx.x * 16 + lx;
    const int h  = blockIdx.y * 16 + ly;
    const int n  = blockIdx.z;

    // Affine params (block-uniform: whole block shares one n).
    const float theta = params[n * 5 + 0];
    const float psx   = params[n * 5 + 1];
    const float psy   = params[n * 5 + 2];
    const float ptx   = params[n * 5 + 3];
    const float pty   = params[n * 5 + 4];
    const float st = sinf(theta);
    const float ct = cosf(theta);
    const float a = psx * ct, b = -st,      cc = ptx;
    const float d = st,       e = psy * ct, f  = pty;

    // ---- per-pixel sample coords + bilinear weights (identical math to the
    // verified gather kernel; LDS path returns bit-identical values) ----
    const float ix = src_coord(a, b, cc, w, h);
    const float iy = src_coord(d, e, f,  w, h);

    const float x0f = floorf(ix);
    const float y0f = floorf(iy);
    const float x1f = x0f + 1.0f;
    const float y1f = y0f + 1.0f;
    const float wx1 = ix - x0f, wx0 = 1.0f - wx1;
    const float wy1 = iy - y0f, wy0 = 1.0f - wy1;

    // Zero-padding validity: weight zeroed when UNclamped coord is outside.
    const float vx0 = (x0f >= 0.0f && x0f <= (float)(W_ - 1)) ? 1.0f : 0.0f;
    const float vx1 = (x1f >= 0.0f && x1f <= (float)(W_ - 1)) ? 1.0f : 0.0f;
    const float vy0 = (y0f >= 0.0f && y0f <= (float)(H_ - 1)) ? 1.0f : 0.0f;
    const float vy1 = (y1f >= 0.0f && y1f <= (float)(H_ - 1)) ? 1.0f : 0.0f;

    const float w00 = wy0 * wx0 * vy0 * vx0;
    const float w01 = wy0 * wx1 * vy0 * vx1;
    const float w10 = wy1 * wx0 * vy1 * vx0;
    const float w11 = wy1 * wx1 * vy1 * vx1;

    const int x0i = (int)x0f, y0i = (int)y0f;
    const int x0c = min(max(x0i,     0), W_ - 1);
    const int x1c = min(max(x0i + 1, 0), W_ - 1);
    const int y0c = min(max(y0i,     0), H_ - 1);
    const int y1c = min(max(y0i + 1, 0), H_ - 1);

    // ---- block-uniform source bbox from the 16x16 tile's corners ----
    const int w0 = blockIdx.x * 16, w1 = w0 + 15;
    const int h0 = blockIdx.y * 16, h1 = h0 + 15;
    const float cx00 = src_coord(a, b, cc, w0, h0);
    const float cx10 = src_coord(a, b, cc, w1, h0);
    const float cx01 = src_coord(a, b, cc, w0, h1);
    const float cx11 = src_coord(a, b, cc, w1, h1);
    const float cy00 = src_coord(d, e, f,  w0, h0);
    const float cy10 = src_coord(d, e, f,  w1, h0);
    const float cy01 = src_coord(d, e, f,  w0, h1);
    const float cy11 = src_coord(d, e, f,  w1, h1);
    const float ixmin = fminf(fminf(cx00, cx10), fminf(cx01, cx11));
    const float ixmax = fmaxf(fmaxf(cx00, cx10), fmaxf(cx01, cx11));
    const float iymin = fminf(fminf(cy00, cy10), fminf(cy01, cy11));
    const float iymax = fmaxf(fmaxf(cy00, cy10), fmaxf(cy01, cy11));

    // +-1 fp safety margin; clamp monotonically so every clamped tap coord
    // lands inside [lo, hi].
    int xlo = (int)floorf(ixmin) - 1, xhi = (int)floorf(ixmax) + 2;
    int ylo = (int)floorf(iymin) - 1, yhi = (int)floorf(iymax) + 2;
    xlo = min(max(xlo, 0), W_ - 1);  xhi = min(max(xhi, 0), W_ - 1);
    ylo = min(max(ylo, 0), H_ - 1);  yhi = min(max(yhi, 0), H_ - 1);
    const int bw = xhi - xlo + 1;
    const int bh = yhi - ylo + 1;

    const float* __restrict__ p = x + (size_t)n * C_ * H_ * W_;
    float* __restrict__ o = out + (((size_t)n * C_) * SH_ + h) * SW_ + w;

    if (bw <= LDSW && bh <= LDSH) {
        // ---- LDS-staged path: coalesced row loads, gather from LDS ----
        // Channel-invariant LDS byte offsets (x1c/y1c may equal x0c/y0c at
        // the image edge, so compute each independently).
        const int l00 = (y0c - ylo) * LDSS + (x0c - xlo);
        const int l01 = (y0c - ylo) * LDSS + (x1c - xlo);
        const int l10 = (y1c - ylo) * LDSS + (x0c - xlo);
        const int l11 = (y1c - ylo) * LDSS + (x1c - xlo);

        const float* __restrict__ ps = p + ylo * W_ + xlo;
#pragma unroll 1
        for (int ch = 0; ch < C_; ++ch) {
            __syncthreads();   // previous iteration's samples done before overwrite
            for (int r = ly; r < bh; r += 16)
                for (int cx = lx; cx < bw; cx += 16)
                    tile[r * LDSS + cx] = ps[r * W_ + cx];
            __syncthreads();
            const float v00 = tile[l00];
            const float v01 = tile[l01];
            const float v10 = tile[l10];
            const float v11 = tile[l11];
            *o = v00 * w00 + v01 * w01 + v10 * w10 + v11 * w11;
            ps += H_ * W_;
            o  += SH_ * SW_;
        }
    } else {
        // ---- fallback: direct gather (the verified 786 us kernel's loop) ----
        const int off00 = y0c * W_ + x0c;
        const int off01 = y0c * W_ + x1c;
        const int off10 = y1c * W_ + x0c;
        const int off11 = y1c * W_ + x1c;
#pragma unroll 8
        for (int ch = 0; ch < C_; ++ch) {
            const float v00 = p[off00];
            const float v01 = p[off01];
            const float v10 = p[off10];
            const float v11 = p[off11];
            *o = v00 * w00 + v01 * w01 + v10 * w10 + v11 * w11;
            p += H_ * W_;
            o += SH_ * SW_;
        }
    }
}

extern "C" void kernel_launch(void* const* d_in, const int* in_sizes, int n_in,
                              void* d_out, int out_size, void* d_ws, size_t ws_size,
                              hipStream_t stream) {
    const float* x      = (const float*)d_in[0];
    const float* params = (const float*)d_in[1];
    float* out = (float*)d_out;

    dim3 block(16, 16, 1);
    dim3 grid(SW_ / 16, SH_ / 16, N_); // 16 x 16 x 16 = 4096 blocks
    affine_sample_kernel<<<grid, block, 0, stream>>>(x, params, out);
}

// Round 2
// 772.405 us; speedup vs baseline: 1.1413x; 1.1413x over previous
//
#include <hip/hip_runtime.h>

// Problem shape (fixed): x (16,32,512,512) fp32, params (16,5) fp32,
// small_h = small_w = 256. Output (16,32,256,256) fp32.
constexpr int N_  = 16;
constexpr int C_  = 32;
constexpr int H_  = 512;
constexpr int W_  = 512;
constexpr int SH_ = 256;
constexpr int SW_ = 256;

// Staged source window per 16x16 output tile, per channel.
// Affine bound: |a|+|b| <= sqrt(2) (sx,sy,theta in [0,1)), so the source
// span of a 16x16 tile is <= 30*sqrt(2) = 42.5 px; +1 (x1 tap) +1 (floor)
// +2 (fp margin) -> bbox <= 47x47. Staged window: 48 rows x 64 floats,
// xstart 4-float aligned (16B global loads). Block-uniform fallback to
// direct gather if the bbox ever exceeds the window.
constexpr int RH = 48;   // staged rows
constexpr int RW = 64;   // staged row width (floats)
constexpr int RS = 68;   // LDS row stride floats; 68*4=272B (16B-multiple,
                         // +4-bank shift per row -> kills same-col conflicts)

__device__ __forceinline__ float src_coord(float ca, float cb, float cbias,
                                           int wk, int hk) {
    const float gx = (2.0f * (float)(2 * wk) + 1.0f) * (1.0f / (float)W_) - 1.0f;
    const float gy = (2.0f * (float)(2 * hk) + 1.0f) * (1.0f / (float)H_) - 1.0f;
    const float s  = ca * gx + cb * gy + cbias;
    return ((s + 1.0f) * (float)W_ - 1.0f) * 0.5f;
}

__global__ __launch_bounds__(256) void affine_sample_kernel(
    const float* __restrict__ x,      // (N, C, H, W)
    const float* __restrict__ params, // (N, 5): theta, sx, sy, tx, ty
    float* __restrict__ out)          // (N, C, SH, SW)
{
    __shared__ float tile[2][RH * RS];   // 2 channels in flight, 26112 B

    const int lx = threadIdx.x;
    const int ly = threadIdx.y;
    const int w  = blockIdx.x * 16 + lx;
    const int h  = blockIdx.y * 16 + ly;
    const int n  = blockIdx.z;

    const float theta = params[n * 5 + 0];
    const float psx   = params[n * 5 + 1];
    const float psy   = params[n * 5 + 2];
    const float ptx   = params[n * 5 + 3];
    const float pty   = params[n * 5 + 4];
    const float st = sinf(theta);
    const float ct = cosf(theta);
    const float a = psx * ct, b = -st,      cc = ptx;
    const float d = st,       e = psy * ct, f  = pty;

    // ---- per-pixel sample coords + bilinear weights (bit-identical to the
    // verified gather kernel) ----
    const float ix = src_coord(a, b, cc, w, h);
    const float iy = src_coord(d, e, f,  w, h);

    const float x0f = floorf(ix);
    const float y0f = floorf(iy);
    const float x1f = x0f + 1.0f;
    const float y1f = y0f + 1.0f;
    const float wx1 = ix - x0f, wx0 = 1.0f - wx1;
    const float wy1 = iy - y0f, wy0 = 1.0f - wy1;

    const float vx0 = (x0f >= 0.0f && x0f <= (float)(W_ - 1)) ? 1.0f : 0.0f;
    const float vx1 = (x1f >= 0.0f && x1f <= (float)(W_ - 1)) ? 1.0f : 0.0f;
    const float vy0 = (y0f >= 0.0f && y0f <= (float)(H_ - 1)) ? 1.0f : 0.0f;
    const float vy1 = (y1f >= 0.0f && y1f <= (float)(H_ - 1)) ? 1.0f : 0.0f;

    const float w00 = wy0 * wx0 * vy0 * vx0;
    const float w01 = wy0 * wx1 * vy0 * vx1;
    const float w10 = wy1 * wx0 * vy1 * vx0;
    const float w11 = wy1 * wx1 * vy1 * vx1;

    const int x0i = (int)x0f, y0i = (int)y0f;
    const int x0c = min(max(x0i,     0), W_ - 1);
    const int x1c = min(max(x0i + 1, 0), W_ - 1);
    const int y0c = min(max(y0i,     0), H_ - 1);
    const int y1c = min(max(y0i + 1, 0), H_ - 1);

    // ---- block-uniform source bbox from tile corners ----
    const int w0 = blockIdx.x * 16, w1 = w0 + 15;
    const int h0 = blockIdx.y * 16, h1 = h0 + 15;
    const float cx00 = src_coord(a, b, cc, w0, h0);
    const float cx10 = src_coord(a, b, cc, w1, h0);
    const float cx01 = src_coord(a, b, cc, w0, h1);
    const float cx11 = src_coord(a, b, cc, w1, h1);
    const float cy00 = src_coord(d, e, f,  w0, h0);
    const float cy10 = src_coord(d, e, f,  w1, h0);
    const float cy01 = src_coord(d, e, f,  w0, h1);
    const float cy11 = src_coord(d, e, f,  w1, h1);
    const float ixmin = fminf(fminf(cx00, cx10), fminf(cx01, cx11));
    const float ixmax = fmaxf(fmaxf(cx00, cx10), fmaxf(cx01, cx11));
    const float iymin = fminf(fminf(cy00, cy10), fminf(cy01, cy11));
    const float iymax = fmaxf(fmaxf(cy00, cy10), fmaxf(cy01, cy11));

    int xlo = (int)floorf(ixmin) - 1, xhi = (int)floorf(ixmax) + 2;
    int ylo = (int)floorf(iymin) - 1, yhi = (int)floorf(iymax) + 2;
    xlo = min(max(xlo, 0), W_ - 1);  xhi = min(max(xhi, 0), W_ - 1);
    ylo = min(max(ylo, 0), H_ - 1);  yhi = min(max(yhi, 0), H_ - 1);
    const int bw = xhi - xlo + 1;
    const int bh = yhi - ylo + 1;

    const float* __restrict__ p = x + (size_t)n * C_ * H_ * W_;
    float* __restrict__ o = out + (((size_t)n * C_) * SH_ + h) * SW_ + w;

    // Coverage guarantees (see window derivation):
    //   xstart = min(xlo & ~3, W-RW)  covers [xlo, xhi] iff bw <= RW-3
    //   ystart = min(ylo, H-RH)       covers [ylo, yhi] iff bh <= RH
    if (bw <= RW - 3 && bh <= RH) {
        const int xstart = min(xlo & ~3, W_ - RW);   // 16B-aligned window
        const int ystart = min(ylo, H_ - RH);

        // Channel-invariant LDS tap offsets.
        const int l00 = (y0c - ystart) * RS + (x0c - xstart);
        const int l01 = (y0c - ystart) * RS + (x1c - xstart);
        const int l10 = (y1c - ystart) * RS + (x0c - xstart);
        const int l11 = (y1c - ystart) * RS + (x1c - xstart);

        // Staging assignment: tid = ly*16+lx; quad q = tid&15 (16 float4 per
        // 64-float row), base row r0 = tid>>4; each thread covers rows
        // r0, r0+16, r0+32 of the 48-row window -> 3 float4 loads/channel.
        const int tid = ly * 16 + lx;
        const int q  = (tid & 15) * 4;          // float offset within row
        const int r0 = tid >> 4;

        const float* __restrict__ g = p + (size_t)ystart * W_ + xstart;
        const size_t chs = (size_t)H_ * W_;

        // Prologue: load channels 0 and 1 into registers.
        float4 va0 = *(const float4*)(g + (size_t)(r0     ) * W_ + q);
        float4 va1 = *(const float4*)(g + (size_t)(r0 + 16) * W_ + q);
        float4 va2 = *(const float4*)(g + (size_t)(r0 + 32) * W_ + q);
        float4 vb0 = *(const float4*)(g + chs + (size_t)(r0     ) * W_ + q);
        float4 vb1 = *(const float4*)(g + chs + (size_t)(r0 + 16) * W_ + q);
        float4 vb2 = *(const float4*)(g + chs + (size_t)(r0 + 32) * W_ + q);

        for (int ch = 0; ch < C_; ch += 2) {
            __syncthreads();   // WAR: previous pair's sampling done
            *(float4*)(&tile[0][(r0     ) * RS + q]) = va0;
            *(float4*)(&tile[0][(r0 + 16) * RS + q]) = va1;
            *(float4*)(&tile[0][(r0 + 32) * RS + q]) = va2;
            *(float4*)(&tile[1][(r0     ) * RS + q]) = vb0;
            *(float4*)(&tile[1][(r0 + 16) * RS + q]) = vb1;
            *(float4*)(&tile[1][(r0 + 32) * RS + q]) = vb2;
            __syncthreads();   // staged data visible to all waves

            // Issue next pair's global loads BEFORE sampling: their latency
            // hides under the 8 LDS taps + 2 stores + barrier below.
            if (ch + 2 < C_) {
                g += 2 * chs;
                va0 = *(const float4*)(g + (size_t)(r0     ) * W_ + q);
                va1 = *(const float4*)(g + (size_t)(r0 + 16) * W_ + q);
                va2 = *(const float4*)(g + (size_t)(r0 + 32) * W_ + q);
                vb0 = *(const float4*)(g + chs + (size_t)(r0     ) * W_ + q);
                vb1 = *(const float4*)(g + chs + (size_t)(r0 + 16) * W_ + q);
                vb2 = *(const float4*)(g + chs + (size_t)(r0 + 32) * W_ + q);
            }

            const float s0 = tile[0][l00] * w00 + tile[0][l01] * w01
                           + tile[0][l10] * w10 + tile[0][l11] * w11;
            const float s1 = tile[1][l00] * w00 + tile[1][l01] * w01
                           + tile[1][l10] * w10 + tile[1][l11] * w11;
            o[0]                   = s0;
            o[(size_t)SH_ * SW_]   = s1;
            o += 2 * (size_t)SH_ * SW_;
        }
    } else {
        // ---- fallback: direct gather (the verified 786 us kernel's loop) ----
        const int off00 = y0c * W_ + x0c;
        const int off01 = y0c * W_ + x1c;
        const int off10 = y1c * W_ + x0c;
        const int off11 = y1c * W_ + x1c;
        const float* __restrict__ pf = p;
#pragma unroll 8
        for (int ch = 0; ch < C_; ++ch) {
            const float v00 = pf[off00];
            const float v01 = pf[off01];
            const float v10 = pf[off10];
            const float v11 = pf[off11];
            *o = v00 * w00 + v01 * w01 + v10 * w10 + v11 * w11;
            pf += (size_t)H_ * W_;
            o  += (size_t)SH_ * SW_;
        }
    }
}

extern "C" void kernel_launch(void* const* d_in, const int* in_sizes, int n_in,
                              void* d_out, int out_size, void* d_ws, size_t ws_size,
                              hipStream_t stream) {
    const float* x      = (const float*)d_in[0];
    const float* params = (const float*)d_in[1];
    float* out = (float*)d_out;

    dim3 block(16, 16, 1);
    dim3 grid(SW_ / 16, SH_ / 16, N_); // 16 x 16 x 16 = 4096 blocks
    affine_sample_kernel<<<grid, block, 0, stream>>>(x, params, out);
}